// Round 1
// baseline (69.857 us; speedup 1.0000x reference)
//
#include <hip/hip_runtime.h>
#include <math.h>

// Batched 3x3 polar decomposition via scaled Newton iteration.
// X_{k+1} = 0.5 * (zeta * X + (1/zeta) * X^{-T}),  zeta = |det X|^{-1/3}
// converges quadratically to the orthogonal polar factor U*V^T of the SVD.

#define POLAR_ITERS 12

__global__ __launch_bounds__(256) void polar3x3_kernel(
    const float* __restrict__ rot,   // [n,3,3]
    const float* __restrict__ mat,   // [3,3] broadcast
    float* __restrict__ out,         // [n,3,3] then logdet [n] appended
    int n)
{
    int i = blockIdx.x * blockDim.x + threadIdx.x;
    if (i >= n) return;

    // Uniform 3x3 parameter (compiler scalarizes: uniform pointer + const offsets)
    const float m00 = mat[0], m01 = mat[1], m02 = mat[2];
    const float m10 = mat[3], m11 = mat[4], m12 = mat[5];
    const float m20 = mat[6], m21 = mat[7], m22 = mat[8];

    const float* r = rot + (size_t)i * 9;
    const float r00 = r[0], r01 = r[1], r02 = r[2];
    const float r10 = r[3], r11 = r[4], r12 = r[5];
    const float r20 = r[6], r21 = r[7], r22 = r[8];

    // X = mat @ rot   (x[a][c] = sum_b m[a][b] * r[b][c])
    float x00 = m00*r00 + m01*r10 + m02*r20;
    float x01 = m00*r01 + m01*r11 + m02*r21;
    float x02 = m00*r02 + m01*r12 + m02*r22;
    float x10 = m10*r00 + m11*r10 + m12*r20;
    float x11 = m10*r01 + m11*r11 + m12*r21;
    float x12 = m10*r02 + m11*r12 + m12*r22;
    float x20 = m20*r00 + m21*r10 + m22*r20;
    float x21 = m20*r01 + m21*r11 + m22*r21;
    float x22 = m20*r02 + m21*r12 + m22*r22;

    #pragma unroll
    for (int it = 0; it < POLAR_ITERS; ++it) {
        // Cofactor matrix C:  X^{-T} = C / det(X)
        float c00 = x11*x22 - x12*x21;
        float c01 = x12*x20 - x10*x22;
        float c02 = x10*x21 - x11*x20;
        float c10 = x02*x21 - x01*x22;
        float c11 = x00*x22 - x02*x20;
        float c12 = x01*x20 - x00*x21;
        float c20 = x01*x12 - x02*x11;
        float c21 = x02*x10 - x00*x12;
        float c22 = x00*x11 - x01*x10;

        float det  = x00*c00 + x01*c01 + x02*c02;
        float adet = fmaxf(fabsf(det), 1e-30f);

        // zeta = adet^{-1/3}  (determinant scaling for fast convergence)
        float zeta   = exp2f(-log2f(adet) * (1.0f / 3.0f));
        float invdet = copysignf(1.0f / adet, det);

        float s = 0.5f * zeta;           // scale on X
        float t = 0.5f * invdet / zeta;  // scale on cofactor (-> X^{-T})

        x00 = s*x00 + t*c00;  x01 = s*x01 + t*c01;  x02 = s*x02 + t*c02;
        x10 = s*x10 + t*c10;  x11 = s*x11 + t*c11;  x12 = s*x12 + t*c12;
        x20 = s*x20 + t*c20;  x21 = s*x21 + t*c21;  x22 = s*x22 + t*c22;
    }

    float* o = out + (size_t)i * 9;
    o[0] = x00; o[1] = x01; o[2] = x02;
    o[3] = x10; o[4] = x11; o[5] = x12;
    o[6] = x20; o[7] = x21; o[8] = x22;

    // logdet output (second tuple element): zeros, appended after n*9 floats
    out[(size_t)n * 9 + i] = 0.0f;
}

extern "C" void kernel_launch(void* const* d_in, const int* in_sizes, int n_in,
                              void* d_out, int out_size, void* d_ws, size_t ws_size,
                              hipStream_t stream) {
    const float* rot = (const float*)d_in[0];
    const float* mat = (const float*)d_in[1];
    float* out = (float*)d_out;

    int n = in_sizes[0] / 9;
    int block = 256;
    int grid = (n + block - 1) / block;
    polar3x3_kernel<<<grid, block, 0, stream>>>(rot, mat, out, n);
}

// Round 2
// 34.676 us; speedup vs baseline: 2.0146x; 2.0146x over previous
//
#include <hip/hip_runtime.h>
#include <math.h>

// Batched 3x3 polar decomposition: out = polar(mat @ rot[n]) = U @ V^T.
// 7 det-scaled Newton iterations (X <- 0.5*(z*X + sign(det)*z^2*Cof(X)),
// z = |det|^{-1/3}; note z^-1 * X^{-T} = sign(det)*z^2*Cof(X), so NO division)
// + 2 Newton-Schulz polish iterations (pure FMA).
// I/O staged through LDS for fully-coalesced float4 global traffic.

#define NEWTON_ITERS 7
#define NS_ITERS 2

__global__ __launch_bounds__(256) void polar3x3_kernel(
    const float* __restrict__ rot,   // [n,3,3]
    const float* __restrict__ mat,   // [3,3] broadcast
    float* __restrict__ out,         // [n,3,3] then logdet [n] appended
    int n)
{
    __shared__ float lds[2304];      // 256 matrices * 9 floats
    const int t = threadIdx.x;
    const int blockBase = blockIdx.x * 256;
    const int i = blockBase + t;
    const bool full = (blockBase + 256 <= n);

    // ---- load 256 matrices, coalesced float4 (192 lanes x 3) ----
    if (full) {
        const float4* src4 = (const float4*)(rot + (size_t)blockBase * 9);
        float4* lds4 = (float4*)lds;
        if (t < 192) {
            #pragma unroll
            for (int k = 0; k < 3; ++k) lds4[t + 192 * k] = src4[t + 192 * k];
        }
    } else {
        for (int j = t; j < 2304; j += 256) {
            int g = blockBase * 9 + j;
            lds[j] = (g < n * 9) ? rot[g] : 0.0f;
        }
    }
    __syncthreads();

    // own matrix from LDS (word stride 9: odd -> 2-way bank alias, free)
    const float r00 = lds[t*9+0], r01 = lds[t*9+1], r02 = lds[t*9+2];
    const float r10 = lds[t*9+3], r11 = lds[t*9+4], r12 = lds[t*9+5];
    const float r20 = lds[t*9+6], r21 = lds[t*9+7], r22 = lds[t*9+8];
    __syncthreads();   // before reusing lds for output

    // uniform 3x3 parameter
    const float m00 = mat[0], m01 = mat[1], m02 = mat[2];
    const float m10 = mat[3], m11 = mat[4], m12 = mat[5];
    const float m20 = mat[6], m21 = mat[7], m22 = mat[8];

    // X = mat @ rot
    float x00 = m00*r00 + m01*r10 + m02*r20;
    float x01 = m00*r01 + m01*r11 + m02*r21;
    float x02 = m00*r02 + m01*r12 + m02*r22;
    float x10 = m10*r00 + m11*r10 + m12*r20;
    float x11 = m10*r01 + m11*r11 + m12*r21;
    float x12 = m10*r02 + m11*r12 + m12*r22;
    float x20 = m20*r00 + m21*r10 + m22*r20;
    float x21 = m20*r01 + m21*r11 + m22*r21;
    float x22 = m20*r02 + m21*r12 + m22*r22;

    #pragma unroll
    for (int it = 0; it < NEWTON_ITERS; ++it) {
        float c00 = x11*x22 - x12*x21;
        float c01 = x12*x20 - x10*x22;
        float c02 = x10*x21 - x11*x20;
        float c10 = x02*x21 - x01*x22;
        float c11 = x00*x22 - x02*x20;
        float c12 = x01*x20 - x00*x21;
        float c20 = x01*x12 - x02*x11;
        float c21 = x02*x10 - x00*x12;
        float c22 = x00*x11 - x01*x10;

        float det  = x00*c00 + x01*c01 + x02*c02;
        float adet = fmaxf(fabsf(det), 1e-30f);

        // zeta = adet^(-1/3) via HW log2/exp2 (1 instr each)
        float l    = __builtin_amdgcn_logf(adet);
        float zeta = __builtin_amdgcn_exp2f(l * (-1.0f / 3.0f));

        float s = 0.5f * zeta;                        // on X
        float u = copysignf(0.5f * zeta * zeta, det); // on Cof(X)  (= 0.5*z^-1/det)

        x00 = s*x00 + u*c00;  x01 = s*x01 + u*c01;  x02 = s*x02 + u*c02;
        x10 = s*x10 + u*c10;  x11 = s*x11 + u*c11;  x12 = s*x12 + u*c12;
        x20 = s*x20 + u*c20;  x21 = s*x21 + u*c21;  x22 = s*x22 + u*c22;
    }

    // Newton-Schulz polish: X <- X * (1.5 I - 0.5 X^T X), pure FMA
    #pragma unroll
    for (int it = 0; it < NS_ITERS; ++it) {
        float s00 = x00*x00 + x10*x10 + x20*x20;
        float s01 = x00*x01 + x10*x11 + x20*x21;
        float s02 = x00*x02 + x10*x12 + x20*x22;
        float s11 = x01*x01 + x11*x11 + x21*x21;
        float s12 = x01*x02 + x11*x12 + x21*x22;
        float s22 = x02*x02 + x12*x12 + x22*x22;
        float t00 = 1.5f - 0.5f*s00, t01 = -0.5f*s01, t02 = -0.5f*s02;
        float t11 = 1.5f - 0.5f*s11, t12 = -0.5f*s12;
        float t22 = 1.5f - 0.5f*s22;
        float y00 = x00*t00 + x01*t01 + x02*t02;
        float y01 = x00*t01 + x01*t11 + x02*t12;
        float y02 = x00*t02 + x01*t12 + x02*t22;
        float y10 = x10*t00 + x11*t01 + x12*t02;
        float y11 = x10*t01 + x11*t11 + x12*t12;
        float y12 = x10*t02 + x11*t12 + x12*t22;
        float y20 = x20*t00 + x21*t01 + x22*t02;
        float y21 = x20*t01 + x21*t11 + x22*t12;
        float y22 = x20*t02 + x21*t12 + x22*t22;
        x00=y00; x01=y01; x02=y02;
        x10=y10; x11=y11; x12=y12;
        x20=y20; x21=y21; x22=y22;
    }

    // ---- stage result to LDS, then coalesced float4 stores ----
    lds[t*9+0]=x00; lds[t*9+1]=x01; lds[t*9+2]=x02;
    lds[t*9+3]=x10; lds[t*9+4]=x11; lds[t*9+5]=x12;
    lds[t*9+6]=x20; lds[t*9+7]=x21; lds[t*9+8]=x22;
    __syncthreads();

    if (full) {
        float4* dst4 = (float4*)(out + (size_t)blockBase * 9);
        const float4* lds4 = (const float4*)lds;
        if (t < 192) {
            #pragma unroll
            for (int k = 0; k < 3; ++k) dst4[t + 192 * k] = lds4[t + 192 * k];
        }
        // logdet zeros: 256 floats = 64 float4
        if (t < 64) {
            float4* ld4 = (float4*)(out + (size_t)n * 9 + blockBase);
            ld4[t] = make_float4(0.f, 0.f, 0.f, 0.f);
        }
    } else {
        for (int j = t; j < 2304; j += 256) {
            int g = blockBase * 9 + j;
            if (g < n * 9) out[g] = lds[j];
        }
        if (i < n) out[(size_t)n * 9 + i] = 0.0f;
    }
}

extern "C" void kernel_launch(void* const* d_in, const int* in_sizes, int n_in,
                              void* d_out, int out_size, void* d_ws, size_t ws_size,
                              hipStream_t stream) {
    const float* rot = (const float*)d_in[0];
    const float* mat = (const float*)d_in[1];
    float* out = (float*)d_out;

    int n = in_sizes[0] / 9;
    int block = 256;
    int grid = (n + block - 1) / block;
    polar3x3_kernel<<<grid, block, 0, stream>>>(rot, mat, out, n);
}

// Round 3
// 32.326 us; speedup vs baseline: 2.1610x; 1.0727x over previous
//
#include <hip/hip_runtime.h>
#include <math.h>

// Batched 3x3 polar decomposition, TWO matrices per thread packed into
// float2 vectors so the FMA-heavy math selects v_pk_fma_f32 (full-rate
// packed fp32 on gfx950 -- scalar fp32 FMA is half rate).
// 6 det-scaled Newton iterations + 2 Newton-Schulz polish.
// Global I/O staged through LDS as coalesced float4.

typedef float v2f __attribute__((ext_vector_type(2)));

#define NEWTON_ITERS 6
#define NS_ITERS 2

__global__ __launch_bounds__(256) void polar3x3_pk_kernel(
    const float* __restrict__ rot,   // [n,3,3]
    const float* __restrict__ mat,   // [3,3] broadcast
    float* __restrict__ out,         // [n,3,3] then logdet[n]
    int n)
{
    __shared__ float lds[4608];      // 512 matrices * 9 floats
    const int t = threadIdx.x;
    const long long base = (long long)blockIdx.x * 512;   // first matrix of block
    const bool full = (base + 512 <= (long long)n);

    // ---- load 512 matrices = 1152 float4, coalesced ----
    if (full) {
        const float4* s4 = (const float4*)(rot + base * 9);
        float4* l4 = (float4*)lds;
        #pragma unroll
        for (int k = 0; k < 5; ++k) {
            int idx = t + 256 * k;
            if (idx < 1152) l4[idx] = s4[idx];
        }
    } else {
        for (int j = t; j < 4608; j += 256) {
            long long g = base * 9 + j;
            lds[j] = (g < (long long)n * 9) ? rot[g] : 0.0f;
        }
    }
    __syncthreads();

    // ---- own pair of matrices (elements j and j+9 -> ds_read2_b32) ----
    const float* L = lds + t * 18;
    v2f r00 = {L[0], L[9]},  r01 = {L[1], L[10]}, r02 = {L[2], L[11]};
    v2f r10 = {L[3], L[12]}, r11 = {L[4], L[13]}, r12 = {L[5], L[14]};
    v2f r20 = {L[6], L[15]}, r21 = {L[7], L[16]}, r22 = {L[8], L[17]};

    const float m00 = mat[0], m01 = mat[1], m02 = mat[2];
    const float m10 = mat[3], m11 = mat[4], m12 = mat[5];
    const float m20 = mat[6], m21 = mat[7], m22 = mat[8];

    // X = mat @ rot  (packed across the two matrices)
    v2f x00 = m00*r00 + m01*r10 + m02*r20;
    v2f x01 = m00*r01 + m01*r11 + m02*r21;
    v2f x02 = m00*r02 + m01*r12 + m02*r22;
    v2f x10 = m10*r00 + m11*r10 + m12*r20;
    v2f x11 = m10*r01 + m11*r11 + m12*r21;
    v2f x12 = m10*r02 + m11*r12 + m12*r22;
    v2f x20 = m20*r00 + m21*r10 + m22*r20;
    v2f x21 = m20*r01 + m21*r11 + m22*r21;
    v2f x22 = m20*r02 + m21*r12 + m22*r22;

    #pragma unroll
    for (int it = 0; it < NEWTON_ITERS; ++it) {
        v2f c00 = x11*x22 - x12*x21;
        v2f c01 = x12*x20 - x10*x22;
        v2f c02 = x10*x21 - x11*x20;
        v2f c10 = x02*x21 - x01*x22;
        v2f c11 = x00*x22 - x02*x20;
        v2f c12 = x01*x20 - x00*x21;
        v2f c20 = x01*x12 - x02*x11;
        v2f c21 = x02*x10 - x00*x12;
        v2f c22 = x00*x11 - x01*x10;

        v2f det = x00*c00 + x01*c01 + x02*c02;

        // per-matrix scalar scaling: z = |det|^(-1/3)
        float d0 = det.x, d1 = det.y;
        float ad0 = fmaxf(fabsf(d0), 1e-30f);
        float ad1 = fmaxf(fabsf(d1), 1e-30f);
        float z0 = __builtin_amdgcn_exp2f(__builtin_amdgcn_logf(ad0) * (-1.0f/3.0f));
        float z1 = __builtin_amdgcn_exp2f(__builtin_amdgcn_logf(ad1) * (-1.0f/3.0f));
        v2f s = {0.5f * z0, 0.5f * z1};
        v2f u = {copysignf(0.5f * z0 * z0, d0), copysignf(0.5f * z1 * z1, d1)};

        x00 = s*x00 + u*c00;  x01 = s*x01 + u*c01;  x02 = s*x02 + u*c02;
        x10 = s*x10 + u*c10;  x11 = s*x11 + u*c11;  x12 = s*x12 + u*c12;
        x20 = s*x20 + u*c20;  x21 = s*x21 + u*c21;  x22 = s*x22 + u*c22;
    }

    // Newton-Schulz polish: X <- X * (1.5 I - 0.5 X^T X), pure packed FMA
    #pragma unroll
    for (int it = 0; it < NS_ITERS; ++it) {
        v2f s00 = x00*x00 + x10*x10 + x20*x20;
        v2f s01 = x00*x01 + x10*x11 + x20*x21;
        v2f s02 = x00*x02 + x10*x12 + x20*x22;
        v2f s11 = x01*x01 + x11*x11 + x21*x21;
        v2f s12 = x01*x02 + x11*x12 + x21*x22;
        v2f s22 = x02*x02 + x12*x12 + x22*x22;
        v2f t00 = 1.5f - 0.5f*s00, t01 = -0.5f*s01, t02 = -0.5f*s02;
        v2f t11 = 1.5f - 0.5f*s11, t12 = -0.5f*s12;
        v2f t22 = 1.5f - 0.5f*s22;
        v2f y00 = x00*t00 + x01*t01 + x02*t02;
        v2f y01 = x00*t01 + x01*t11 + x02*t12;
        v2f y02 = x00*t02 + x01*t12 + x02*t22;
        v2f y10 = x10*t00 + x11*t01 + x12*t02;
        v2f y11 = x10*t01 + x11*t11 + x12*t12;
        v2f y12 = x10*t02 + x11*t12 + x12*t22;
        v2f y20 = x20*t00 + x21*t01 + x22*t02;
        v2f y21 = x20*t01 + x21*t11 + x22*t12;
        v2f y22 = x20*t02 + x21*t12 + x22*t22;
        x00=y00; x01=y01; x02=y02;
        x10=y10; x11=y11; x12=y12;
        x20=y20; x21=y21; x22=y22;
    }

    // ---- stage results (same region this thread read; no barrier needed) ----
    float* S = lds + t * 18;
    S[0]=x00.x; S[9]=x00.y;  S[1]=x01.x; S[10]=x01.y;  S[2]=x02.x; S[11]=x02.y;
    S[3]=x10.x; S[12]=x10.y; S[4]=x11.x; S[13]=x11.y;  S[5]=x12.x; S[14]=x12.y;
    S[6]=x20.x; S[15]=x20.y; S[7]=x21.x; S[16]=x21.y;  S[8]=x22.x; S[17]=x22.y;
    __syncthreads();

    if (full) {
        float4* d4 = (float4*)(out + base * 9);
        const float4* l4 = (const float4*)lds;
        #pragma unroll
        for (int k = 0; k < 5; ++k) {
            int idx = t + 256 * k;
            if (idx < 1152) d4[idx] = l4[idx];
        }
        // logdet zeros: 512 floats = 128 float4
        if (t < 128) {
            float4* ld4 = (float4*)(out + (long long)n * 9 + base);
            ld4[t] = make_float4(0.f, 0.f, 0.f, 0.f);
        }
    } else {
        for (int j = t; j < 4608; j += 256) {
            long long g = base * 9 + j;
            if (g < (long long)n * 9) out[g] = lds[j];
        }
        for (int j = t; j < 512; j += 256) {
            long long i2 = base + j;
            if (i2 < (long long)n) out[(long long)n * 9 + i2] = 0.0f;
        }
    }
}

extern "C" void kernel_launch(void* const* d_in, const int* in_sizes, int n_in,
                              void* d_out, int out_size, void* d_ws, size_t ws_size,
                              hipStream_t stream) {
    const float* rot = (const float*)d_in[0];
    const float* mat = (const float*)d_in[1];
    float* out = (float*)d_out;

    int n = in_sizes[0] / 9;
    int block = 256;
    int grid = (n + 511) / 512;   // 512 matrices per block, 2 per thread
    polar3x3_pk_kernel<<<grid, block, 0, stream>>>(rot, mat, out, n);
}

// Round 5
// 29.702 us; speedup vs baseline: 2.3519x; 1.0883x over previous
//
#include <hip/hip_runtime.h>
#include <math.h>

// Batched 3x3 polar decomposition, wave-autonomous version:
//  - each wave stages its own 128 matrices global->LDS via global_load_lds
//    (linear dest, 4x16B + 2x4B per lane), NO __syncthreads anywhere
//  - 2 matrices/thread packed into float2 vectors -> v_pk_fma_f32
//  - 6 det-scaled Newton iterations + 2 Newton-Schulz polish
//  - results re-staged in the wave's LDS region, stored as nontemporal
//    (clang ext_vector types -- HIP float4 wrapper is rejected by the builtin)

typedef float v2f __attribute__((ext_vector_type(2)));
typedef float v4f __attribute__((ext_vector_type(4)));

#define NEWTON_ITERS 6
#define NS_ITERS 2

__device__ __forceinline__ void polar_pair(
    v2f& x00, v2f& x01, v2f& x02,
    v2f& x10, v2f& x11, v2f& x12,
    v2f& x20, v2f& x21, v2f& x22)
{
    #pragma unroll
    for (int it = 0; it < NEWTON_ITERS; ++it) {
        v2f c00 = x11*x22 - x12*x21;
        v2f c01 = x12*x20 - x10*x22;
        v2f c02 = x10*x21 - x11*x20;
        v2f c10 = x02*x21 - x01*x22;
        v2f c11 = x00*x22 - x02*x20;
        v2f c12 = x01*x20 - x00*x21;
        v2f c20 = x01*x12 - x02*x11;
        v2f c21 = x02*x10 - x00*x12;
        v2f c22 = x00*x11 - x01*x10;

        v2f det = x00*c00 + x01*c01 + x02*c02;

        float d0 = det.x, d1 = det.y;
        float ad0 = fmaxf(fabsf(d0), 1e-30f);
        float ad1 = fmaxf(fabsf(d1), 1e-30f);
        float z0 = __builtin_amdgcn_exp2f(__builtin_amdgcn_logf(ad0) * (-1.0f/3.0f));
        float z1 = __builtin_amdgcn_exp2f(__builtin_amdgcn_logf(ad1) * (-1.0f/3.0f));
        v2f s = {0.5f * z0, 0.5f * z1};
        v2f u = {copysignf(0.5f * z0 * z0, d0), copysignf(0.5f * z1 * z1, d1)};

        x00 = s*x00 + u*c00;  x01 = s*x01 + u*c01;  x02 = s*x02 + u*c02;
        x10 = s*x10 + u*c10;  x11 = s*x11 + u*c11;  x12 = s*x12 + u*c12;
        x20 = s*x20 + u*c20;  x21 = s*x21 + u*c21;  x22 = s*x22 + u*c22;
    }

    #pragma unroll
    for (int it = 0; it < NS_ITERS; ++it) {
        v2f s00 = x00*x00 + x10*x10 + x20*x20;
        v2f s01 = x00*x01 + x10*x11 + x20*x21;
        v2f s02 = x00*x02 + x10*x12 + x20*x22;
        v2f s11 = x01*x01 + x11*x11 + x21*x21;
        v2f s12 = x01*x02 + x11*x12 + x21*x22;
        v2f s22 = x02*x02 + x12*x12 + x22*x22;
        v2f t00 = 1.5f - 0.5f*s00, t01 = -0.5f*s01, t02 = -0.5f*s02;
        v2f t11 = 1.5f - 0.5f*s11, t12 = -0.5f*s12;
        v2f t22 = 1.5f - 0.5f*s22;
        v2f y00 = x00*t00 + x01*t01 + x02*t02;
        v2f y01 = x00*t01 + x01*t11 + x02*t12;
        v2f y02 = x00*t02 + x01*t12 + x02*t22;
        v2f y10 = x10*t00 + x11*t01 + x12*t02;
        v2f y11 = x10*t01 + x11*t11 + x12*t12;
        v2f y12 = x10*t02 + x11*t12 + x12*t22;
        v2f y20 = x20*t00 + x21*t01 + x22*t02;
        v2f y21 = x20*t01 + x21*t11 + x22*t12;
        v2f y22 = x20*t02 + x21*t12 + x22*t22;
        x00=y00; x01=y01; x02=y02;
        x10=y10; x11=y11; x12=y12;
        x20=y20; x21=y21; x22=y22;
    }
}

__global__ __launch_bounds__(256) void polar3x3_wave_kernel(
    const float* __restrict__ rot,   // [n,3,3]
    const float* __restrict__ mat,   // [3,3] broadcast
    float* __restrict__ out,         // [n,3,3] then logdet[n]
    int n)
{
    __shared__ float lds[4608];              // 4 waves * 1152 floats
    const int t    = threadIdx.x;
    const int lane = t & 63;
    const int w    = t >> 6;
    const long long blockBase = (long long)blockIdx.x * 512;  // matrices
    const long long waveBase  = blockBase + (long long)w * 128;
    float* wlds = lds + w * 1152;

    // uniform parameter (scalar loads, overlap with staging)
    const float m00 = mat[0], m01 = mat[1], m02 = mat[2];
    const float m10 = mat[3], m11 = mat[4], m12 = mat[5];
    const float m20 = mat[6], m21 = mat[7], m22 = mat[8];

    const bool full = (blockBase + 512 <= (long long)n);

    v2f r00, r01, r02, r10, r11, r12, r20, r21, r22;

    if (full) {
        // ---- wave-local staging: 1152 floats, linear, no barrier ----
        const float* gsrc = rot + waveBase * 9;
        #pragma unroll
        for (int k = 0; k < 4; ++k) {
            __builtin_amdgcn_global_load_lds(
                (const __attribute__((address_space(1))) void*)(gsrc + k * 256 + lane * 4),
                (__attribute__((address_space(3))) void*)(wlds + k * 256),
                16, 0, 0);
        }
        #pragma unroll
        for (int k = 0; k < 2; ++k) {
            __builtin_amdgcn_global_load_lds(
                (const __attribute__((address_space(1))) void*)(gsrc + 1024 + k * 64 + lane),
                (__attribute__((address_space(3))) void*)(wlds + 1024 + k * 64),
                4, 0, 0);
        }
        asm volatile("s_waitcnt vmcnt(0)" ::: "memory");

        const float* L = wlds + lane * 18;   // this lane's 2 matrices
        r00 = v2f{L[0], L[9]};  r01 = v2f{L[1], L[10]}; r02 = v2f{L[2], L[11]};
        r10 = v2f{L[3], L[12]}; r11 = v2f{L[4], L[13]}; r12 = v2f{L[5], L[14]};
        r20 = v2f{L[6], L[15]}; r21 = v2f{L[7], L[16]}; r22 = v2f{L[8], L[17]};
    } else {
        // tail block: direct guarded scalar loads, identity padding
        #pragma unroll
        for (int q = 0; q < 2; ++q) {
            long long mi = waveBase + 2 * lane + q;
            if (mi < (long long)n) {
                const float* r = rot + mi * 9;
                r00[q]=r[0]; r01[q]=r[1]; r02[q]=r[2];
                r10[q]=r[3]; r11[q]=r[4]; r12[q]=r[5];
                r20[q]=r[6]; r21[q]=r[7]; r22[q]=r[8];
            } else {
                r00[q]=1.f; r01[q]=0.f; r02[q]=0.f;
                r10[q]=0.f; r11[q]=1.f; r12[q]=0.f;
                r20[q]=0.f; r21[q]=0.f; r22[q]=1.f;
            }
        }
    }

    // X = mat @ rot
    v2f x00 = m00*r00 + m01*r10 + m02*r20;
    v2f x01 = m00*r01 + m01*r11 + m02*r21;
    v2f x02 = m00*r02 + m01*r12 + m02*r22;
    v2f x10 = m10*r00 + m11*r10 + m12*r20;
    v2f x11 = m10*r01 + m11*r11 + m12*r21;
    v2f x12 = m10*r02 + m11*r12 + m12*r22;
    v2f x20 = m20*r00 + m21*r10 + m22*r20;
    v2f x21 = m20*r01 + m21*r11 + m22*r21;
    v2f x22 = m20*r02 + m21*r12 + m22*r22;

    polar_pair(x00,x01,x02,x10,x11,x12,x20,x21,x22);

    if (full) {
        // ---- restage results in the wave's own region, store coalesced ----
        float* S = wlds + lane * 18;
        S[0]=x00.x; S[9]=x00.y;  S[1]=x01.x; S[10]=x01.y;  S[2]=x02.x; S[11]=x02.y;
        S[3]=x10.x; S[12]=x10.y; S[4]=x11.x; S[13]=x11.y;  S[5]=x12.x; S[14]=x12.y;
        S[6]=x20.x; S[15]=x20.y; S[7]=x21.x; S[16]=x21.y;  S[8]=x22.x; S[17]=x22.y;
        // wave-local RAW through LDS: compiler inserts lgkmcnt wait (same wave,
        // in-order DS pipe) -- no barrier needed.
        v4f* gdst4 = (v4f*)(out + waveBase * 9);
        const v4f* l4 = (const v4f*)wlds;
        #pragma unroll
        for (int k = 0; k < 4; ++k)
            __builtin_nontemporal_store(l4[k * 64 + lane], gdst4 + k * 64 + lane);
        v2f* gdst2 = (v2f*)(out + waveBase * 9 + 1024);
        const v2f* l2 = (const v2f*)(wlds + 1024);
        __builtin_nontemporal_store(l2[lane], gdst2 + lane);

        // logdet zeros: this wave's 128 entries, float2 per lane
        v2f* ld2 = (v2f*)(out + (long long)n * 9 + waveBase);
        __builtin_nontemporal_store(v2f{0.f, 0.f}, ld2 + lane);
    } else {
        #pragma unroll
        for (int q = 0; q < 2; ++q) {
            long long mi = waveBase + 2 * lane + q;
            if (mi < (long long)n) {
                float* o = out + mi * 9;
                o[0]=x00[q]; o[1]=x01[q]; o[2]=x02[q];
                o[3]=x10[q]; o[4]=x11[q]; o[5]=x12[q];
                o[6]=x20[q]; o[7]=x21[q]; o[8]=x22[q];
                out[(long long)n * 9 + mi] = 0.0f;
            }
        }
    }
}

extern "C" void kernel_launch(void* const* d_in, const int* in_sizes, int n_in,
                              void* d_out, int out_size, void* d_ws, size_t ws_size,
                              hipStream_t stream) {
    const float* rot = (const float*)d_in[0];
    const float* mat = (const float*)d_in[1];
    float* out = (float*)d_out;

    int n = in_sizes[0] / 9;
    int block = 256;
    int grid = (n + 511) / 512;   // 512 matrices per block, 2 per thread
    polar3x3_wave_kernel<<<grid, block, 0, stream>>>(rot, mat, out, n);
}